// Round 1
// baseline (229.650 us; speedup 1.0000x reference)
//
#include <hip/hip_runtime.h>
#include <hip/hip_bf16.h>

// LocalCausalAttention: b=4, t=4096, h=16, d=64, window W=64.
// I/O f32, internal compute bf16 MFMA. One WG (4 waves) per (b, t-block, head).
// R4: LDS 46080->32768 (5 WGs/CU): Q direct-to-registers, XOR-swizzled K/P/sVt
//     (no pads), validity via wave ballots, XCD-aware jb swizzle.
//
// Swizzle convention (16B units within a row):
//   K  [128][64]:  (row,col) -> row*64  + (((col>>3) ^ (row&7 )) << 3) + (col&7)
//   P  [ 64][128]: (r,  c )  -> r*128   + (((c  >>3) ^ (r  &15)) << 3) + (c  &7)
//   sVt[ 64][128]: (d, key)  -> d*128   + (((key>>3) ^ (d  &15)) << 3) + (key&7)

#define TT 4096
#define HH 16
#define DD 64
#define WW 64
#define NBLK (TT / WW)

typedef __attribute__((ext_vector_type(8))) short bf16x8;
typedef __attribute__((ext_vector_type(4))) float f32x4;

static __device__ __forceinline__ ushort f2bf(float x) {
    return __builtin_bit_cast(unsigned short, __float2bfloat16(x));
}
static __device__ __forceinline__ uint pack2(float a, float b) {
    return (uint)f2bf(a) | ((uint)f2bf(b) << 16);
}

__global__ __launch_bounds__(256, 5)
void lca_fwd(const float* __restrict__ q, const float* __restrict__ k,
             const float* __restrict__ v, const int* __restrict__ am,
             float* __restrict__ out)
{
    // XCD-aware bijective swizzle: 8 XCDs, gridDim.x = 64 -> XCD x owns jb in [8x, 8x+8)
    // so neighboring t-blocks (shared 64-row K/V halo) hit the same L2.
    const int jb = ((blockIdx.x & 7) << 3) | (blockIdx.x >> 3);
    const int hi = blockIdx.y;
    const int bi = blockIdx.z;

    __shared__ ushort sKP[8192];   // K bf16 (QK^T), then P bf16 (PV) — 16 KB
    __shared__ ushort sVt[8192];   // V^T bf16 [d][key] — 16 KB           (total 32768 B)

    const int tid  = threadIdx.x;
    const int wv   = tid >> 6, lane = tid & 63;
    const int quad = lane >> 4, l15 = lane & 15;

    const size_t rowstride = (size_t)HH * DD;
    const size_t qbase = ((size_t)(bi * TT + jb * WW) * HH + hi) * DD;
    const long  kstart = (long)jb * WW - WW;

    // ---- validity via ballots (no LDS): keys 0..63 = prev block, 64..127 = cur block (== q mask) ----
    const int* amb = am + (size_t)bi * TT;
    long t0 = kstart + lane;
    bool kv0 = (t0 >= 0) && (amb[t0] != 0);
    bool qv  = (amb[jb * WW + lane] != 0);
    unsigned long long kvm_lo = __ballot(kv0);
    unsigned long long qvm    = __ballot(qv);   // also the key mask for cols 64..127

    // ---- batched global loads: all 20 float4 in flight before converts ----
    float4 fk[8], fv[8], fq[4];
    if (jb > 0) {
        #pragma unroll
        for (int p = 0; p < 8; ++p) {
            int idx = p * 256 + tid;
            int row = idx >> 4, c4 = (idx & 15) * 4;
            fk[p] = *(const float4*)(k + ((size_t)(bi * TT + kstart + row) * HH + hi) * DD + c4);
        }
        #pragma unroll
        for (int p = 0; p < 8; ++p) {
            int idx = p * 256 + tid;
            int row = idx >> 4, c4 = (idx & 15) * 4;
            fv[p] = *(const float4*)(v + ((size_t)(bi * TT + kstart + row) * HH + hi) * DD + c4);
        }
    } else {
        // jb==0: rows 0..63 are the zero-pad block; p>=4 <=> row>=64 (uniform per iter)
        #pragma unroll
        for (int p = 0; p < 8; ++p) {
            float4 z = make_float4(0.f, 0.f, 0.f, 0.f);
            if (p >= 4) {
                int idx = p * 256 + tid;
                int row = idx >> 4, c4 = (idx & 15) * 4;
                z = *(const float4*)(k + ((size_t)(bi * TT + (row - 64)) * HH + hi) * DD + c4);
            }
            fk[p] = z;
        }
        #pragma unroll
        for (int p = 0; p < 8; ++p) {
            float4 z = make_float4(0.f, 0.f, 0.f, 0.f);
            if (p >= 4) {
                int idx = p * 256 + tid;
                int row = idx >> 4, c4 = (idx & 15) * 4;
                z = *(const float4*)(v + ((size_t)(bi * TT + (row - 64)) * HH + hi) * DD + c4);
            }
            fv[p] = z;
        }
    }
    // Q A-fragments straight to registers: rows 16wv+l15, k-slices quad*8(+4), 32+quad*8(+4)
    {
        const float* qrow = q + qbase + (size_t)(16 * wv + l15) * rowstride;
        fq[0] = *(const float4*)(qrow + quad * 8);
        fq[1] = *(const float4*)(qrow + quad * 8 + 4);
        fq[2] = *(const float4*)(qrow + 32 + quad * 8);
        fq[3] = *(const float4*)(qrow + 32 + quad * 8 + 4);
    }

    // ---- convert + LDS writes ----
    #pragma unroll
    for (int p = 0; p < 8; ++p) {
        int idx = p * 256 + tid;
        int row = idx >> 4, c4 = (idx & 15) * 4;
        uint2 w; w.x = pack2(fk[p].x, fk[p].y); w.y = pack2(fk[p].z, fk[p].w);
        *(uint2*)(&sKP[row * 64 + (((c4 >> 3) ^ (row & 7)) << 3) + (c4 & 7)]) = w;
    }
    #pragma unroll
    for (int p = 0; p < 8; ++p) {
        int idx = p * 256 + tid;
        int row = idx >> 4, c4 = (idx & 15) * 4;   // row = key, c4 = d0
        int u = row >> 3, k7 = row & 7;
        sVt[(c4 + 0) * 128 + ((u ^ ((c4 + 0) & 15)) << 3) + k7] = f2bf(fv[p].x);
        sVt[(c4 + 1) * 128 + ((u ^ ((c4 + 1) & 15)) << 3) + k7] = f2bf(fv[p].y);
        sVt[(c4 + 2) * 128 + ((u ^ ((c4 + 2) & 15)) << 3) + k7] = f2bf(fv[p].z);
        sVt[(c4 + 3) * 128 + ((u ^ ((c4 + 3) & 15)) << 3) + k7] = f2bf(fv[p].w);
    }
    union { bf16x8 v8; uint u[4]; } A0, A1;
    A0.u[0] = pack2(fq[0].x, fq[0].y); A0.u[1] = pack2(fq[0].z, fq[0].w);
    A0.u[2] = pack2(fq[1].x, fq[1].y); A0.u[3] = pack2(fq[1].z, fq[1].w);
    A1.u[0] = pack2(fq[2].x, fq[2].y); A1.u[1] = pack2(fq[2].z, fq[2].w);
    A1.u[2] = pack2(fq[3].x, fq[3].y); A1.u[3] = pack2(fq[3].z, fq[3].w);
    __syncthreads();   // staging complete

    const int r0 = 16 * wv + 4 * quad;
    const int r7 = l15 & 7;

    // ---- S = Q K^T : wave wv owns S rows [16wv,16wv+16) x 128 cols ----
    f32x4 acc[8];
    #pragma unroll
    for (int kt = 0; kt < 8; ++kt) {
        f32x4 a = {0.f, 0.f, 0.f, 0.f};
        const ushort* kr = &sKP[(16 * kt + l15) * 64];
        bf16x8 b0 = *(const bf16x8*)(kr + ((quad ^ r7) << 3));
        bf16x8 b1 = *(const bf16x8*)(kr + (((4 + quad) ^ r7) << 3));
        a = __builtin_amdgcn_mfma_f32_16x16x32_bf16(A0.v8, b0, a, 0, 0, 0);
        a = __builtin_amdgcn_mfma_f32_16x16x32_bf16(A1.v8, b1, a, 0, 0, 0);
        acc[kt] = a;
    }
    __syncthreads();   // all waves done reading K before P overlays it

    // ---- masked softmax ----
    const float NEG = -1.0e9f;
    float rmax[4] = {NEG, NEG, NEG, NEG};
    #pragma unroll
    for (int kt = 0; kt < 8; ++kt) {
        int c = 16 * kt + l15;
        unsigned long long km = (kt < 4) ? kvm_lo : qvm;
        int kvc = (int)((km >> (c & 63)) & 1ull);
        #pragma unroll
        for (int reg = 0; reg < 4; ++reg) {
            int r = r0 + reg;
            bool valid = (c > r) && (c <= r + WW) && kvc;
            float s = valid ? acc[kt][reg] : NEG;
            acc[kt][reg] = s;
            rmax[reg] = fmaxf(rmax[reg], s);
        }
    }
    #pragma unroll
    for (int reg = 0; reg < 4; ++reg) {
        #pragma unroll
        for (int m = 1; m <= 8; m <<= 1)
            rmax[reg] = fmaxf(rmax[reg], __shfl_xor(rmax[reg], m, 64));
    }

    const float CEXP = 0.125f * 1.44269504088896f;  // scale * log2(e)
    const int l7 = l15 & 7, h3 = l15 >> 3;
    float rsum[4] = {0.f, 0.f, 0.f, 0.f};
    #pragma unroll
    for (int kt = 0; kt < 8; ++kt) {
        int cu = 2 * kt + h3;                        // c >> 3
        #pragma unroll
        for (int reg = 0; reg < 4; ++reg) {
            float s = acc[kt][reg];
            float pex = (s > -1.0e8f) ? exp2f((s - rmax[reg]) * CEXP) : 0.f;
            rsum[reg] += pex;
            int r = r0 + reg;                        // r & 15 == 4*quad + reg
            sKP[r * 128 + ((cu ^ (4 * quad + reg)) << 3) + l7] = f2bf(pex);
        }
    }
    float rden[4];
    #pragma unroll
    for (int reg = 0; reg < 4; ++reg) {
        #pragma unroll
        for (int m = 1; m <= 8; m <<= 1)
            rsum[reg] += __shfl_xor(rsum[reg], m, 64);
        rden[reg] = (rsum[reg] > 0.f ? 1.f / rsum[reg] : 0.f)
                    * (float)((qvm >> (r0 + reg)) & 1ull);
    }

    // No barrier: wave wv reads only P rows [16wv,16wv+16) it wrote itself,
    // and sVt was synced at the staging barrier.
    bf16x8 ap[4];
    const ushort* pr = &sKP[(16 * wv + l15) * 128];
    #pragma unroll
    for (int kc = 0; kc < 4; ++kc)
        ap[kc] = *(const bf16x8*)(pr + (((4 * kc + quad) ^ l15) << 3));

    #pragma unroll
    for (int nt = 0; nt < 4; ++nt) {
        f32x4 a = {0.f, 0.f, 0.f, 0.f};
        const ushort* vr = &sVt[(16 * nt + l15) * 128];
        #pragma unroll
        for (int kc = 0; kc < 4; ++kc) {
            bf16x8 bv = *(const bf16x8*)(vr + (((4 * kc + quad) ^ l15) << 3));
            a = __builtin_amdgcn_mfma_f32_16x16x32_bf16(ap[kc], bv, a, 0, 0, 0);
        }
        #pragma unroll
        for (int reg = 0; reg < 4; ++reg)
            out[qbase + (size_t)(r0 + reg) * rowstride + 16 * nt + l15]
                = a[reg] * rden[reg];
    }
}

extern "C" void kernel_launch(void* const* d_in, const int* in_sizes, int n_in,
                              void* d_out, int out_size, void* d_ws, size_t ws_size,
                              hipStream_t stream) {
    const float* q  = (const float*)d_in[0];
    const float* k  = (const float*)d_in[1];
    const float* v  = (const float*)d_in[2];
    const int*   am = (const int*)d_in[3];
    float* out = (float*)d_out;

    const int b = in_sizes[3] / TT;   // 4
    dim3 grid(NBLK, HH, b);
    dim3 block(256);
    lca_fwd<<<grid, block, 0, stream>>>(q, k, v, am, out);
}

// Round 2
// 229.337 us; speedup vs baseline: 1.0014x; 1.0014x over previous
//
#include <hip/hip_runtime.h>
#include <hip/hip_bf16.h>

// LocalCausalAttention: b=4, t=4096, h=16, d=64, window W=64.
// R5: pipelined multi-block WG. One WG (4 waves) handles NBJ=8 consecutive
// t-blocks for one (b,head): halo reuse (each block stages only ONE new
// 64-row K half + V half + Q), T14 issue-early/write-late staging so HBM
// latency hides under the previous block's compute. LDS = 32KB:
//   sK[2] ring of 64-row K halves; the dead half doubles as the P region
//   (P written in two 8KB passes: keys 0-63 before PV phase1, 64-127 after).
//   sV[2] ring of V^T halves.
// Grid 512 WGs = 2/CU (tail-free); bet is ILP not TLP (R4 showed TLP~0).

#define TT 4096
#define HH 16
#define DD 64
#define WW 64
#define NBLK (TT / WW)
#define NBJ 8
#define NGRP (NBLK / NBJ)

typedef __attribute__((ext_vector_type(8))) short bf16x8;
typedef __attribute__((ext_vector_type(4))) float f32x4;

static __device__ __forceinline__ ushort f2bf(float x) {
    return __builtin_bit_cast(unsigned short, __float2bfloat16(x));
}
static __device__ __forceinline__ uint pack2(float a, float b) {
    return (uint)f2bf(a) | ((uint)f2bf(b) << 16);
}

__global__ __launch_bounds__(256, 2)
void lca_fwd(const float* __restrict__ q, const float* __restrict__ k,
             const float* __restrict__ v, const int* __restrict__ am,
             float* __restrict__ out)
{
    const int grp = blockIdx.x;          // block-group (8 t-blocks)
    const int hi  = blockIdx.y;          // head
    const int bi  = blockIdx.z;          // batch
    const int jb0 = grp * NBJ;

    // Half-buffers, 8KB each. sK[pb] = keys 0..63 (H_{j-1}) -> P region -> next K half.
    __shared__ ushort sK[2][4096];
    __shared__ ushort sV[2][4096];       // V^T halves [d][key]

    const int tid  = threadIdx.x;
    const int wv   = tid >> 6, lane = tid & 63;
    const int quad = lane >> 4, l15 = lane & 15;
    const int r0   = 16 * wv + 4 * quad;

    const size_t rowstride = (size_t)HH * DD;
    const size_t tbase = ((size_t)bi * TT * HH + hi) * DD;   // + t*rowstride + c
    const int* amb = am + (size_t)bi * TT;

    // staging decomposition: thread covers rows {srow+16p}, cols sc4..sc4+3
    const int srow = tid >> 4;
    const int sc4  = (tid & 15) * 4;

    auto kload = [&](float4* dst, int m) {
        #pragma unroll
        for (int p = 0; p < 4; ++p) {
            int row = p * 16 + srow;
            dst[p] = *(const float4*)(k + tbase + (size_t)(64 * m + row) * rowstride + sc4);
        }
    };
    auto vload = [&](float4* dst, int m) {
        #pragma unroll
        for (int p = 0; p < 4; ++p) {
            int row = p * 16 + srow;
            dst[p] = *(const float4*)(v + tbase + (size_t)(64 * m + row) * rowstride + sc4);
        }
    };
    auto qload = [&](float4* dst, int j) {
        const float* qrow = q + tbase + (size_t)(64 * j + 16 * wv + l15) * rowstride;
        dst[0] = *(const float4*)(qrow + quad * 8);
        dst[1] = *(const float4*)(qrow + quad * 8 + 4);
        dst[2] = *(const float4*)(qrow + 32 + quad * 8);
        dst[3] = *(const float4*)(qrow + 32 + quad * 8 + 4);
    };
    // K half [64 rows][64 d], swizzle: unit = (c>>3) ^ (row&7)
    auto kstore = [&](ushort* buf, const float4* src) {
        #pragma unroll
        for (int p = 0; p < 4; ++p) {
            int row = p * 16 + srow;
            uint2 w; w.x = pack2(src[p].x, src[p].y); w.y = pack2(src[p].z, src[p].w);
            *(uint2*)(&buf[row * 64 + ((((sc4 >> 3) ^ (row & 7)) & 7) << 3) + (sc4 & 7)]) = w;
        }
    };
    // V^T half [64 d][64 key], swizzle: unit = (key>>3) ^ (((d>>2)^d)&7)
    auto vstore = [&](ushort* buf, const float4* src) {
        #pragma unroll
        for (int p = 0; p < 4; ++p) {
            int row = p * 16 + srow;            // key
            int u = row >> 3, k7 = row & 7;
            float vals[4] = {src[p].x, src[p].y, src[p].z, src[p].w};
            #pragma unroll
            for (int jj = 0; jj < 4; ++jj) {
                int d = sc4 + jj;
                int fd = ((d >> 2) ^ d) & 7;
                buf[d * 64 + (((u ^ fd) & 7) << 3) + k7] = f2bf(vals[jj]);
            }
        }
    };

    // ---- prologue: stage halves H_{jb0-1}, H_{jb0} ----
    {
        float4 a[4], b[4];
        if (jb0 > 0) {
            kload(a, jb0 - 1); vload(b, jb0 - 1);
            kstore(sK[0], a);  vstore(sV[0], b);
        } else {
            #pragma unroll
            for (int p = 0; p < 4; ++p) {
                *(uint2*)(&sK[0][(p * 256 + tid) * 4]) = make_uint2(0u, 0u);
                *(uint2*)(&sV[0][(p * 256 + tid) * 4]) = make_uint2(0u, 0u);
            }
        }
        kload(a, jb0); vload(b, jb0);
        kstore(sK[1], a); vstore(sV[1], b);
    }
    float4 fqc[4];
    qload(fqc, jb0);
    unsigned long long qvm_prev = 0;
    if (jb0 > 0) qvm_prev = __ballot(amb[(jb0 - 1) * 64 + lane] != 0);
    __syncthreads();

    const int swl = l15 & 7;
    const int fdl = ((l15 >> 2) ^ l15) & 7;
    const float NEG = -1.0e9f;
    const float CEXP = 0.125f * 1.44269504088896f;   // scale * log2(e)

    for (int bj = 0; bj < NBJ; ++bj) {
        const int j  = jb0 + bj;
        const int pb = bj & 1;
        ushort* kP = sK[pb];      // keys 0..63 (H_{j-1}); then P region; then H_{j+1}
        ushort* kC = sK[pb ^ 1];  // keys 64..127 (H_j)
        ushort* vP = sV[pb];      // V^T keys 0..63
        ushort* vC = sV[pb ^ 1];  // V^T keys 64..127

        // masks (kvm for keys 0..63 carried from previous block's qvm)
        unsigned long long qvm = __ballot(amb[j * 64 + lane] != 0);
        unsigned long long kvm_lo = qvm_prev;
        qvm_prev = qvm;

        // T14 issue-early: next block's fresh half + Q straight into regs
        float4 nk[4], nv[4], fqn[4];
        if (bj < NBJ - 1) { kload(nk, j + 1); vload(nv, j + 1); qload(fqn, j + 1); }

        // convert current Q to A-frags
        union { bf16x8 v8; uint u[4]; } A0, A1;
        A0.u[0] = pack2(fqc[0].x, fqc[0].y); A0.u[1] = pack2(fqc[0].z, fqc[0].w);
        A0.u[2] = pack2(fqc[1].x, fqc[1].y); A0.u[3] = pack2(fqc[1].z, fqc[1].w);
        A1.u[0] = pack2(fqc[2].x, fqc[2].y); A1.u[1] = pack2(fqc[2].z, fqc[2].w);
        A1.u[2] = pack2(fqc[3].x, fqc[3].y); A1.u[3] = pack2(fqc[3].z, fqc[3].w);

        // ---- S = Q K^T ----
        f32x4 acc[8];
        #pragma unroll
        for (int kt = 0; kt < 8; ++kt) {
            const ushort* kr = (kt < 4 ? kP : kC) + (16 * (kt & 3) + l15) * 64;
            bf16x8 b0 = *(const bf16x8*)(kr + (((quad    ) ^ swl) << 3));
            bf16x8 b1 = *(const bf16x8*)(kr + (((4 + quad) ^ swl) << 3));
            f32x4 a = {0.f, 0.f, 0.f, 0.f};
            a = __builtin_amdgcn_mfma_f32_16x16x32_bf16(A0.v8, b0, a, 0, 0, 0);
            a = __builtin_amdgcn_mfma_f32_16x16x32_bf16(A1.v8, b1, a, 0, 0, 0);
            acc[kt] = a;
        }
        __syncthreads();   // B1: kP free of K readers -> becomes P region

        // ---- masked softmax ----
        float rmax[4] = {NEG, NEG, NEG, NEG};
        #pragma unroll
        for (int kt = 0; kt < 8; ++kt) {
            int c = 16 * kt + l15;
            unsigned long long km = (kt < 4) ? kvm_lo : qvm;
            int kvc = (int)((km >> (c & 63)) & 1ull);
            #pragma unroll
            for (int reg = 0; reg < 4; ++reg) {
                int r = r0 + reg;
                bool valid = (c > r) && (c <= r + WW) && kvc;
                float s = valid ? acc[kt][reg] : NEG;
                acc[kt][reg] = s;
                rmax[reg] = fmaxf(rmax[reg], s);
            }
        }
        #pragma unroll
        for (int reg = 0; reg < 4; ++reg)
            #pragma unroll
            for (int m = 1; m <= 8; m <<= 1)
                rmax[reg] = fmaxf(rmax[reg], __shfl_xor(rmax[reg], m, 64));

        float rsum[4] = {0.f, 0.f, 0.f, 0.f};
        #pragma unroll
        for (int kt = 0; kt < 8; ++kt)
            #pragma unroll
            for (int reg = 0; reg < 4; ++reg) {
                float s = acc[kt][reg];
                float pex = (s > -1.0e8f) ? exp2f((s - rmax[reg]) * CEXP) : 0.f;
                rsum[reg] += pex;
                acc[kt][reg] = pex;
            }

        // write P-low (keys 0..63) into kP; swizzle f(r) = (r ^ (r>>3)) & 7
        #pragma unroll
        for (int kt = 0; kt < 4; ++kt) {
            int un = 2 * kt + (l15 >> 3), of = l15 & 7;
            #pragma unroll
            for (int reg = 0; reg < 4; ++reg) {
                int r = r0 + reg;
                kP[r * 64 + (((un ^ ((r ^ (r >> 3)) & 7)) & 7) << 3) + of] = f2bf(acc[kt][reg]);
            }
        }
        float rden[4];
        #pragma unroll
        for (int reg = 0; reg < 4; ++reg) {
            #pragma unroll
            for (int m = 1; m <= 8; m <<= 1)
                rsum[reg] += __shfl_xor(rsum[reg], m, 64);
            rden[reg] = (rsum[reg] > 0.f ? 1.f / rsum[reg] : 0.f)
                        * (float)((qvm >> (r0 + reg)) & 1ull);
        }

        // ---- PV phase 1 (keys 0..63): A = own P rows, B = vP ----
        const int prow = 16 * wv + l15;
        const int psw  = (prow ^ (prow >> 3)) & 7;
        bf16x8 ap0 = *(const bf16x8*)(&kP[prow * 64 + (((quad    ) ^ psw) << 3)]);
        bf16x8 ap1 = *(const bf16x8*)(&kP[prow * 64 + (((4 + quad) ^ psw) << 3)]);
        f32x4 po[4];
        #pragma unroll
        for (int nt = 0; nt < 4; ++nt) {
            int fd = fdl ^ (4 * (nt & 1));
            const ushort* vr = &vP[(16 * nt + l15) * 64];
            bf16x8 bv0 = *(const bf16x8*)(vr + ((((quad    ) ^ fd) & 7) << 3));
            bf16x8 bv1 = *(const bf16x8*)(vr + ((((4 + quad) ^ fd) & 7) << 3));
            f32x4 a = {0.f, 0.f, 0.f, 0.f};
            a = __builtin_amdgcn_mfma_f32_16x16x32_bf16(ap0, bv0, a, 0, 0, 0);
            a = __builtin_amdgcn_mfma_f32_16x16x32_bf16(ap1, bv1, a, 0, 0, 0);
            po[nt] = a;
        }

        // write P-high (keys 64..127) over the same region (own rows only -> no barrier)
        #pragma unroll
        for (int kt = 4; kt < 8; ++kt) {
            int un = 2 * (kt - 4) + (l15 >> 3), of = l15 & 7;
            #pragma unroll
            for (int reg = 0; reg < 4; ++reg) {
                int r = r0 + reg;
                kP[r * 64 + (((un ^ ((r ^ (r >> 3)) & 7)) & 7) << 3) + of] = f2bf(acc[kt][reg]);
            }
        }
        ap0 = *(const bf16x8*)(&kP[prow * 64 + (((quad    ) ^ psw) << 3)]);
        ap1 = *(const bf16x8*)(&kP[prow * 64 + (((4 + quad) ^ psw) << 3)]);
        #pragma unroll
        for (int nt = 0; nt < 4; ++nt) {
            int fd = fdl ^ (4 * (nt & 1));
            const ushort* vr = &vC[(16 * nt + l15) * 64];
            bf16x8 bv0 = *(const bf16x8*)(vr + ((((quad    ) ^ fd) & 7) << 3));
            bf16x8 bv1 = *(const bf16x8*)(vr + ((((4 + quad) ^ fd) & 7) << 3));
            f32x4 a = po[nt];
            a = __builtin_amdgcn_mfma_f32_16x16x32_bf16(ap0, bv0, a, 0, 0, 0);
            a = __builtin_amdgcn_mfma_f32_16x16x32_bf16(ap1, bv1, a, 0, 0, 0);
            po[nt] = a;
        }

        // ---- out stores ----
        const size_t obase = tbase + (size_t)(j * 64) * rowstride;
        #pragma unroll
        for (int nt = 0; nt < 4; ++nt)
            #pragma unroll
            for (int reg = 0; reg < 4; ++reg)
                out[obase + (size_t)(r0 + reg) * rowstride + 16 * nt + l15]
                    = po[nt][reg] * rden[reg];

        // ---- T14 write-late: stage next halves over the dead buffers ----
        if (bj < NBJ - 1) {
            __syncthreads();          // B2: all waves done reading vP + their P region
            kstore(kP, nk);           // H_{j+1}
            vstore(vP, nv);
            fqc[0] = fqn[0]; fqc[1] = fqn[1]; fqc[2] = fqn[2]; fqc[3] = fqn[3];
            __syncthreads();          // B3: staged halves visible before next QK^T
        }
    }
}

extern "C" void kernel_launch(void* const* d_in, const int* in_sizes, int n_in,
                              void* d_out, int out_size, void* d_ws, size_t ws_size,
                              hipStream_t stream) {
    const float* q  = (const float*)d_in[0];
    const float* k  = (const float*)d_in[1];
    const float* v  = (const float*)d_in[2];
    const int*   am = (const int*)d_in[3];
    float* outp = (float*)d_out;

    const int b = in_sizes[3] / TT;   // 4
    dim3 grid(NGRP, HH, b);
    dim3 block(256);
    lca_fwd<<<grid, block, 0, stream>>>(q, k, v, am, outp);
}